// Round 5
// baseline (469.826 us; speedup 1.0000x reference)
//
#include <hip/hip_runtime.h>

typedef _Float16 f16;
typedef _Float16 f16x8 __attribute__((ext_vector_type(8)));
typedef float f32x2 __attribute__((ext_vector_type(2)));
typedef float f32x4 __attribute__((ext_vector_type(4)));
typedef float f32x16 __attribute__((ext_vector_type(16)));
typedef unsigned int u32;
typedef unsigned int u32x4 __attribute__((ext_vector_type(4)));

#define THREADS 512
#define BROWS 256

// d_ws layout (bytes)
#define WS_B1EFF 0                      // 256 f32 (kept for debug)
#define WS_BPERM 1024                   // [5][256] f32: acc-init biases, idx = nt*32 + kh*16 + r
#define WS_W1H   6144                   // [256 n][32 k] f16 (n-major, k<25 valid)  -- NOT swizzled
#define WS_W2H   22528                  // [256 n][256 k] f16, XOR-swizzled: idx ^ ((n&31)<<3)
#define WS_W3H   (WS_W2H + 131072)
#define WS_W4H   (WS_W3H + 131072)
#define WS_W5H   (WS_W4H + 131072)      // [32 n][256 k] f16, rows 9..31 zero -- NOT swizzled
#define WS_END   (WS_W5H + 16384)

// R16 prep: identical to R15.
__global__ void prep_kernel(const float* __restrict__ emb, const int* __restrict__ traj,
                            const float* __restrict__ W1, const float* __restrict__ b1,
                            const float* __restrict__ W2, const float* __restrict__ b2,
                            const float* __restrict__ W3, const float* __restrict__ b3,
                            const float* __restrict__ W4, const float* __restrict__ b4,
                            const float* __restrict__ W5, const float* __restrict__ b5,
                            float* __restrict__ b1eff, float* __restrict__ bperm,
                            f16* __restrict__ W1h, f16* __restrict__ W2h,
                            f16* __restrict__ W3h, f16* __restrict__ W4h,
                            f16* __restrict__ W5h) {
  if (blockIdx.x == 832) {
    __shared__ float lat[128];
    __shared__ float bsh[256];
    int t = *traj;
    if (threadIdx.x < 128) lat[threadIdx.x] = emb[t * 128 + threadIdx.x];
    __syncthreads();
    int n = threadIdx.x;
    float s0 = 0.f, s1 = 0.f, s2 = 0.f, s3 = 0.f;
#pragma unroll 4
    for (int d = 0; d < 128; d += 4) {
      s0 = fmaf(lat[d + 0], W1[(25 + d) * 256 + n], s0);
      s1 = fmaf(lat[d + 1], W1[(26 + d) * 256 + n], s1);
      s2 = fmaf(lat[d + 2], W1[(27 + d) * 256 + n], s2);
      s3 = fmaf(lat[d + 3], W1[(28 + d) * 256 + n], s3);
    }
    float v = b1[n] + ((s0 + s1) + (s2 + s3));
    b1eff[n] = v; bsh[n] = v;
    __syncthreads();
    int i = threadIdx.x;
    int nt = i >> 5, khh = (i >> 4) & 1, r = i & 15;
    int nn = 32 * nt + (r & 3) + 8 * (r >> 2) + 4 * khh;
    bperm[0 * 256 + i] = bsh[nn];
    bperm[1 * 256 + i] = b2[nn];
    bperm[2 * 256 + i] = b3[nn];
    bperm[3 * 256 + i] = b4[nn];
    bperm[4 * 256 + i] = (nn < 9) ? b5[nn] : 0.0f;
    return;
  }
  int i = blockIdx.x * 256 + threadIdx.x;
  if (i < 8192) {
    int n = i >> 5, k = i & 31;
    W1h[i] = (f16)((k < 25) ? W1[k * 256 + n] : 0.0f);
  } else if (i < 73728) {
    int j = i - 8192; int k = j >> 8, n = j & 255;
    W2h[(n * 256 + k) ^ ((n & 31) << 3)] = (f16)W2[j];
  } else if (i < 139264) {
    int j = i - 73728; int k = j >> 8, n = j & 255;
    W3h[(n * 256 + k) ^ ((n & 31) << 3)] = (f16)W3[j];
  } else if (i < 204800) {
    int j = i - 139264; int k = j >> 8, n = j & 255;
    W4h[(n * 256 + k) ^ ((n & 31) << 3)] = (f16)W4[j];
  } else if (i < 212992) {
    int j = i - 204800; int n = j >> 8, k = j & 255;   // n 0..31
    W5h[j] = (f16)((n < 9) ? W5[k * 9 + n] : 0.0f);
  }
}

// Exact-erf GELU on f32x2 (R13-proven bit-identical to the R11 scalar chain).
// DO NOT move to f16 arithmetic (R6: 4.6e-4 fail).
__device__ __forceinline__ f32x2 gelu2(f32x2 z) {
  f32x2 s = z * z;
  f32x2 q = __builtin_elementwise_fma(s, (f32x2)(-1.8889263e-5f), (f32x2)(2.30872094e-4f));
  q = __builtin_elementwise_fma(s, q, (f32x2)(-0.0023746714834f));
  q = __builtin_elementwise_fma(s, q, (f32x2)(0.01994711402007f));
  q = __builtin_elementwise_fma(s, q, (f32x2)(-0.13298076013381f));
  q = __builtin_elementwise_fma(s, q, (f32x2)(0.79788456080287f));
  f32x2 t = z * q;
  f32x2 u = 0.5f * z;
  return __builtin_elementwise_fma(u, t, u);
}

__device__ __forceinline__ u32 pack2(float a, float b) {
  unsigned short ha = __builtin_bit_cast(unsigned short, (f16)a);   // RTE, same as R11
  unsigned short hb = __builtin_bit_cast(unsigned short, (f16)b);
  return (u32)ha | ((u32)hb << 16);
}

// GELU + f16-pack + half-wave exchange (R14/R15-verified: absmax 6.1e-5).
__device__ __forceinline__ void exch_pack(const f32x16 acc, int kh, f16x8* fa, f16x8* fb) {
  float g[16];
#pragma unroll
  for (int i = 0; i < 8; ++i) {
    f32x2 r = gelu2((f32x2){acc[2 * i], acc[2 * i + 1]});
    g[2 * i] = r[0]; g[2 * i + 1] = r[1];
  }
  u32 P[8];
#pragma unroll
  for (int i = 0; i < 8; ++i) P[i] = pack2(g[2 * i], g[2 * i + 1]);
  u32 s[8];
#pragma unroll
  for (int i = 0; i < 8; ++i) s[i] = (u32)__shfl_xor((int)P[i], 32);
  u32x4 ua, ub;
  ua[0] = kh ? s[2] : P[0];
  ua[1] = kh ? s[3] : P[1];
  ua[2] = kh ? P[2] : s[0];
  ua[3] = kh ? P[3] : s[1];
  ub[0] = kh ? s[6] : P[4];
  ub[1] = kh ? s[7] : P[5];
  ub[2] = kh ? P[6] : s[4];
  ub[3] = kh ? P[7] : s[5];
  *fa = __builtin_bit_cast(f16x8, ua);
  *fb = __builtin_bit_cast(f16x8, ub);
}

// Copy one 128KB weight matrix (pre-swizzled source) linearly into LDS.
__device__ __forceinline__ void stage_w(const f16* __restrict__ src, f16* dst, int tid) {
#pragma unroll
  for (int rdi = 0; rdi < 4; ++rdi) {
    f16x8 t0 = *(const f16x8*)(src + (rdi * 4 + 0) * 4096 + tid * 8);
    f16x8 t1 = *(const f16x8*)(src + (rdi * 4 + 1) * 4096 + tid * 8);
    f16x8 t2 = *(const f16x8*)(src + (rdi * 4 + 2) * 4096 + tid * 8);
    f16x8 t3 = *(const f16x8*)(src + (rdi * 4 + 3) * 4096 + tid * 8);
    *(f16x8*)(dst + (rdi * 4 + 0) * 4096 + tid * 8) = t0;
    *(f16x8*)(dst + (rdi * 4 + 1) * 4096 + tid * 8) = t1;
    *(f16x8*)(dst + (rdi * 4 + 2) * 4096 + tid * 8) = t2;
    *(f16x8*)(dst + (rdi * 4 + 3) * 4096 + tid * 8) = t3;
  }
}

// R16 hidden layer: IN-PLACE X update sized to the measured 128-arch/128-AGPR
// split. Phase 1: ALL 8 n-tile accumulators (8 x f32x16 = 128 regs = the AGPR
// half) accumulate over the full K — pairs share B-operand X[kt] (proven-safe
// shared-B/distinct-A/distinct-acc; banned shared-A never occurs). Phase 2:
// after every X read is complete, exch_pack overwrites X[16] in place.
// Per-acc accumulation order unchanged (bias-first, ascending kt) -> bitwise
// identical to R14/R15 (absmax 6.1e-5 proven).
__device__ __forceinline__ void hidden_layer(const f16* Wlds, const float* bp,
                                             f16x8 (&X)[16], int l31, int kh) {
  const int xorm = (l31 & 31) << 3;
  f32x16 acc[8];
#pragma unroll
  for (int t = 0; t < 8; ++t) {
    const f32x4* bq = (const f32x4*)(bp + t * 32);
#pragma unroll
    for (int r = 0; r < 4; ++r) {
      acc[t][r] = bq[0][r]; acc[t][4 + r] = bq[1][r];
      acc[t][8 + r] = bq[2][r]; acc[t][12 + r] = bq[3][r];
    }
  }
#pragma unroll
  for (int tp = 0; tp < 4; ++tp) {
#pragma unroll
    for (int kt = 0; kt < 16; ++kt) {
      const int aA = (((2 * tp) * 32 + l31) * 256 + kt * 16 + kh * 8) ^ xorm;
      const int aB = (((2 * tp + 1) * 32 + l31) * 256 + kt * 16 + kh * 8) ^ xorm;
      f16x8 wA = *(const f16x8*)(Wlds + aA);
      f16x8 wB = *(const f16x8*)(Wlds + aB);
      acc[2 * tp]     = __builtin_amdgcn_mfma_f32_32x32x16_f16(wA, X[kt], acc[2 * tp], 0, 0, 0);
      acc[2 * tp + 1] = __builtin_amdgcn_mfma_f32_32x32x16_f16(wB, X[kt], acc[2 * tp + 1], 0, 0, 0);
    }
  }
#pragma unroll
  for (int t = 0; t < 8; ++t)
    exch_pack(acc[t], kh, &X[2 * t], &X[2 * t + 1]);
}

// R16 = R14/R15 design (register-resident activations, weights through LDS)
// restructured to FIT the measured register split instead of fighting it:
//   - unified budget/wave = 512 / waves-per-EU; 512-thread block => 2/EU =>
//     256 total, split 128 arch / 128 AGPR (R11+R14+R15 all consistent).
//   - single X[16] (64 arch) + 8-acc AGPR phase + in-place pack (above).
//   - Rm stashed in LDS sR (same thread writes/reads: no sync needed);
//     total LDS 140.3KB <= 160KB, still 1 block/CU.
__global__ __launch_bounds__(THREADS, 2) void fused_kernel(
    const float* __restrict__ Fg, const float* __restrict__ Cg,
    const f16* __restrict__ W1h, const f16* __restrict__ W2h,
    const f16* __restrict__ W3h, const f16* __restrict__ W4h,
    const f16* __restrict__ W5h, const float* __restrict__ bperm,
    float* __restrict__ outg, int Btot) {
  __shared__ __align__(16) f16 Wlds[65536];   // 131072 B
  __shared__ __align__(16) float sR[BROWS * 9];  // 9216 B: polar R stash

  const int tid = threadIdx.x;
  const int lane = tid & 63;
  const int wv = tid >> 6;          // 0..7
  const int l31 = lane & 31;
  const int kh = lane >> 5;         // 0/1
  const int lrow = wv * 32 + l31;                     // block-local row
  const int myrow = blockIdx.x * BROWS + lrow;        // both kh halves: same row

  // ---- stage W2 (issue early; consumed after the first barrier) ----
  stage_w(W2h, Wlds, tid);

  // ---- phase A: per-row strain features + polar rotation ----
  float feat[25];
  {
    float Rm[9];
    if (myrow < Btot) {
      float Fm[9], Cm[9];
      const float* fp = Fg + myrow * 9;
      const float* cp = Cg + myrow * 9;
#pragma unroll
      for (int i = 0; i < 9; ++i) Fm[i] = fp[i];
#pragma unroll
      for (int i = 0; i < 9; ++i) Cm[i] = cp[i];
      float G[9];  // F^T F
#pragma unroll
      for (int i = 0; i < 3; ++i)
#pragma unroll
        for (int j = 0; j < 3; ++j)
          G[i * 3 + j] = Fm[i] * Fm[j] + Fm[3 + i] * Fm[3 + j] + Fm[6 + i] * Fm[6 + j];
      float det = Fm[0] * (Fm[4] * Fm[8] - Fm[5] * Fm[7])
                - Fm[1] * (Fm[3] * Fm[8] - Fm[5] * Fm[6])
                + Fm[2] * (Fm[3] * Fm[7] - Fm[4] * Fm[6]);
#pragma unroll
      for (int i = 0; i < 9; ++i) Rm[i] = Fm[i];
#pragma unroll
      for (int it = 0; it < 5; ++it) {
        float c0 = Rm[4]*Rm[8] - Rm[5]*Rm[7];
        float c1 = Rm[5]*Rm[6] - Rm[3]*Rm[8];
        float c2 = Rm[3]*Rm[7] - Rm[4]*Rm[6];
        float c3 = Rm[2]*Rm[7] - Rm[1]*Rm[8];
        float c4 = Rm[0]*Rm[8] - Rm[2]*Rm[6];
        float c5 = Rm[1]*Rm[6] - Rm[0]*Rm[7];
        float c6 = Rm[1]*Rm[5] - Rm[2]*Rm[4];
        float c7 = Rm[2]*Rm[3] - Rm[0]*Rm[5];
        float c8 = Rm[0]*Rm[4] - Rm[1]*Rm[3];
        float dr = Rm[0]*c0 + Rm[1]*c1 + Rm[2]*c2;
        float hv = 0.5f / dr;
        Rm[0] = 0.5f*Rm[0] + hv*c0; Rm[1] = 0.5f*Rm[1] + hv*c1; Rm[2] = 0.5f*Rm[2] + hv*c2;
        Rm[3] = 0.5f*Rm[3] + hv*c3; Rm[4] = 0.5f*Rm[4] + hv*c4; Rm[5] = 0.5f*Rm[5] + hv*c5;
        Rm[6] = 0.5f*Rm[6] + hv*c6; Rm[7] = 0.5f*Rm[7] + hv*c7; Rm[8] = 0.5f*Rm[8] + hv*c8;
      }
      float s00 = Rm[0]*Fm[0] + Rm[3]*Fm[3] + Rm[6]*Fm[6];
      float s11 = Rm[1]*Fm[1] + Rm[4]*Fm[4] + Rm[7]*Fm[7];
      float s22 = Rm[2]*Fm[2] + Rm[5]*Fm[5] + Rm[8]*Fm[8];
      float s01 = 0.5f*((Rm[0]*Fm[1]+Rm[3]*Fm[4]+Rm[6]*Fm[7]) + (Rm[1]*Fm[0]+Rm[4]*Fm[3]+Rm[7]*Fm[6]));
      float s02 = 0.5f*((Rm[0]*Fm[2]+Rm[3]*Fm[5]+Rm[6]*Fm[8]) + (Rm[2]*Fm[0]+Rm[5]*Fm[3]+Rm[8]*Fm[6]));
      float s12 = 0.5f*((Rm[1]*Fm[2]+Rm[4]*Fm[5]+Rm[7]*Fm[8]) + (Rm[2]*Fm[1]+Rm[5]*Fm[4]+Rm[8]*Fm[7]));
      float q  = (s00 + s11 + s22) * (1.0f/3.0f);
      float p1 = s01*s01 + s02*s02 + s12*s12;
      float d0 = s00 - q, d1 = s11 - q, d2 = s22 - q;
      float p2 = d0*d0 + d1*d1 + d2*d2 + 2.0f*p1;
      float p  = sqrtf(p2 * (1.0f/6.0f));
      float e1, e2, e3;
      if (p > 1e-10f) {
        float pi = 1.0f / p;
        float b00 = d0*pi, b11 = d1*pi, b22 = d2*pi;
        float b01 = s01*pi, b02 = s02*pi, b12 = s12*pi;
        float detB = b00*(b11*b22 - b12*b12) - b01*(b01*b22 - b12*b02) + b02*(b01*b12 - b11*b02);
        float r = fminf(fmaxf(0.5f*detB, -1.0f), 1.0f);
        float phi = acosf(r) * (1.0f/3.0f);
        e1 = q + 2.0f * p * cosf(phi);
        e3 = q + 2.0f * p * cosf(phi + 2.0943951023931953f);
        e2 = 3.0f*q - e1 - e3;
      } else { e1 = q; e2 = q; e3 = q; }
      float f00 = fmaxf(Fm[0], 1e-6f);
      feat[0] = e1 - 1.0f; feat[1] = e2 - 1.0f; feat[2] = e3 - 1.0f;
#pragma unroll
      for (int k = 0; k < 9; ++k) feat[3 + k] = G[k];
      feat[3] -= 1.0f; feat[7] -= 1.0f; feat[11] -= 1.0f;
      feat[12] = det - 1.0f;
      feat[13] = logf(det) - 1.0f;
      feat[14] = f00 - 1.0f;
      feat[15] = logf(f00) - 1.0f;
#pragma unroll
      for (int k = 0; k < 9; ++k) feat[16 + k] = Cm[k];
    } else {
#pragma unroll
      for (int k = 0; k < 25; ++k) feat[k] = 0.0f;
#pragma unroll
      for (int k = 0; k < 9; ++k) Rm[k] = 0.0f;
    }
    if (kh == 0) {
#pragma unroll
      for (int k = 0; k < 9; ++k) sR[lrow * 9 + k] = Rm[k];
    }
  }

  // ---- build X1 B-frags (K=32: kt0 = feats 0..15, kt1 = 16..31, pad>=25) ----
  f16x8 xa, xb;
#pragma unroll
  for (int j = 0; j < 8; ++j) xa[j] = (f16)(kh ? feat[8 + j] : feat[j]);
#pragma unroll
  for (int j = 0; j < 8; ++j) {
    int k = 16 + 8 * kh + j;
    xb[j] = (f16)((k < 25) ? feat[k] : 0.0f);
  }

  // ---- L1: W1 (global, [n][32]) x X1 -> X ; paired chains, pack per pair ----
  f16x8 X[16];
  {
    const float* bp = bperm + 0 * 256 + kh * 16;
#pragma unroll
    for (int np = 0; np < 4; ++np) {
      const f32x4* bqA = (const f32x4*)(bp + (2 * np) * 32);
      const f32x4* bqB = (const f32x4*)(bp + (2 * np + 1) * 32);
      f32x16 accA, accB;
#pragma unroll
      for (int r = 0; r < 4; ++r) {
        accA[r] = bqA[0][r]; accA[4 + r] = bqA[1][r]; accA[8 + r] = bqA[2][r]; accA[12 + r] = bqA[3][r];
        accB[r] = bqB[0][r]; accB[4 + r] = bqB[1][r]; accB[8 + r] = bqB[2][r]; accB[12 + r] = bqB[3][r];
      }
      const f16* wbA = W1h + ((2 * np) * 32 + l31) * 32 + kh * 8;
      const f16* wbB = W1h + ((2 * np + 1) * 32 + l31) * 32 + kh * 8;
      f16x8 wA0 = *(const f16x8*)(wbA);
      f16x8 wA1 = *(const f16x8*)(wbA + 16);
      f16x8 wB0 = *(const f16x8*)(wbB);
      f16x8 wB1 = *(const f16x8*)(wbB + 16);
      accA = __builtin_amdgcn_mfma_f32_32x32x16_f16(wA0, xa, accA, 0, 0, 0);
      accB = __builtin_amdgcn_mfma_f32_32x32x16_f16(wB0, xa, accB, 0, 0, 0);
      accA = __builtin_amdgcn_mfma_f32_32x32x16_f16(wA1, xb, accA, 0, 0, 0);
      accB = __builtin_amdgcn_mfma_f32_32x32x16_f16(wB1, xb, accB, 0, 0, 0);
      exch_pack(accA, kh, &X[4 * np], &X[4 * np + 1]);
      exch_pack(accB, kh, &X[4 * np + 2], &X[4 * np + 3]);
    }
  }

  // ---- hidden layers 2..4, in-place X, W staged per layer ----
  __syncthreads();                           // W2 staged visible
  hidden_layer(Wlds, bperm + 1 * 256 + kh * 16, X, l31, kh);

  __syncthreads();                           // all reads of W2 done
  stage_w(W3h, Wlds, tid);
  __syncthreads();                           // W3 staged visible
  hidden_layer(Wlds, bperm + 2 * 256 + kh * 16, X, l31, kh);

  __syncthreads();                           // all reads of W3 done
  stage_w(W4h, Wlds, tid);
  __syncthreads();                           // W4 staged visible
  hidden_layer(Wlds, bperm + 3 * 256 + kh * 16, X, l31, kh);

  // ---- L5: W5 (global, [32][256], rows>=9 zero) x X; n-tile 0 only ----
  f32x16 acc5;
  {
    const float* bp = bperm + 4 * 256 + kh * 16;
    const f32x4* bq = (const f32x4*)(bp);
#pragma unroll
    for (int r = 0; r < 4; ++r) { acc5[r] = bq[0][r]; acc5[4 + r] = bq[1][r]; acc5[8 + r] = bq[2][r]; acc5[12 + r] = bq[3][r]; }
#pragma unroll
    for (int kt = 0; kt < 16; ++kt) {
      f16x8 w = *(const f16x8*)(W5h + l31 * 256 + kt * 16 + kh * 8);
      acc5 = __builtin_amdgcn_mfma_f32_32x32x16_f16(w, X[kt], acc5, 0, 0, 0);
    }
  }

  // ---- final: gather out[0..8] to kh=0 lanes, cauchy = R sym(x) F^T ----
  float sx0 = __shfl_xor(acc5[0], 32);
  float sx1 = __shfl_xor(acc5[1], 32);
  float sx2 = __shfl_xor(acc5[2], 32);
  float sx3 = __shfl_xor(acc5[3], 32);
  if (kh == 0 && myrow < Btot) {
    float x[9];
    x[0] = acc5[0]; x[1] = acc5[1]; x[2] = acc5[2]; x[3] = acc5[3];
    x[4] = sx0; x[5] = sx1; x[6] = sx2; x[7] = sx3;
    x[8] = acc5[4];
    const float* fp = Fg + myrow * 9;
    float Fm[9], Rm[9];
#pragma unroll
    for (int i = 0; i < 9; ++i) Fm[i] = fp[i];
#pragma unroll
    for (int i = 0; i < 9; ++i) Rm[i] = sR[lrow * 9 + i];   // own stash (same thread)
    float y[9];
    y[0] = x[0]; y[4] = x[4]; y[8] = x[8];
    y[1] = 0.5f * (x[1] + x[3]); y[3] = y[1];
    y[2] = 0.5f * (x[2] + x[6]); y[6] = y[2];
    y[5] = 0.5f * (x[5] + x[7]); y[7] = y[5];
    float P[9];
#pragma unroll
    for (int i = 0; i < 3; ++i)
#pragma unroll
      for (int j = 0; j < 3; ++j)
        P[i*3+j] = Rm[i*3]*y[j] + Rm[i*3+1]*y[3+j] + Rm[i*3+2]*y[6+j];
#pragma unroll
    for (int i = 0; i < 3; ++i)
#pragma unroll
      for (int j = 0; j < 3; ++j)
        outg[myrow * 9 + i*3 + j] = P[i*3]*Fm[j*3] + P[i*3+1]*Fm[j*3+1] + P[i*3+2]*Fm[j*3+2];
  }
}

extern "C" void kernel_launch(void* const* d_in, const int* in_sizes, int n_in,
                              void* d_out, int out_size, void* d_ws, size_t ws_size,
                              hipStream_t stream) {
  const float* Fg  = (const float*)d_in[0];
  const float* Cg  = (const float*)d_in[1];
  const float* emb = (const float*)d_in[2];
  const int*   trj = (const int*)d_in[3];
  const float* W1  = (const float*)d_in[4];
  const float* b1  = (const float*)d_in[5];
  const float* W2  = (const float*)d_in[6];
  const float* b2  = (const float*)d_in[7];
  const float* W3  = (const float*)d_in[8];
  const float* b3  = (const float*)d_in[9];
  const float* W4  = (const float*)d_in[10];
  const float* b4  = (const float*)d_in[11];
  const float* W5  = (const float*)d_in[12];
  const float* b5  = (const float*)d_in[13];
  float* outg = (float*)d_out;
  const int Btot = in_sizes[0] / 9;

  char* ws = (char*)d_ws;
  float* b1eff = (float*)(ws + WS_B1EFF);
  float* bperm = (float*)(ws + WS_BPERM);
  f16* W1h = (f16*)(ws + WS_W1H);
  f16* W2h = (f16*)(ws + WS_W2H);
  f16* W3h = (f16*)(ws + WS_W3H);
  f16* W4h = (f16*)(ws + WS_W4H);
  f16* W5h = (f16*)(ws + WS_W5H);

  prep_kernel<<<833, 256, 0, stream>>>(emb, trj, W1, b1, W2, b2, W3, b3, W4, b4,
                                       W5, b5, b1eff, bperm,
                                       W1h, W2h, W3h, W4h, W5h);
  const int grid = (Btot + BROWS - 1) / BROWS;
  fused_kernel<<<grid, THREADS, 0, stream>>>(Fg, Cg, W1h, W2h, W3h, W4h, W5h,
                                             bperm, outg, Btot);
}

// Round 7
// 322.498 us; speedup vs baseline: 1.4568x; 1.4568x over previous
//
#include <hip/hip_runtime.h>

typedef _Float16 f16;
typedef _Float16 f16x8 __attribute__((ext_vector_type(8)));
typedef float f32x4 __attribute__((ext_vector_type(4)));
typedef float f32x16 __attribute__((ext_vector_type(16)));

#define MROWS 64
#define THREADS 512
#define HSTR 264   // f16/row: 528B, 16B-aligned rows (HSTR must be mult. of 8)

// d_ws layout (bytes) — identical to R8/R11 (proven)
#define WS_B1EFF 0                      // 256 f32
#define WS_W1H   1024                   // [256][32] f16 (n-major, k<25 valid, rest 0)
#define WS_W2H   (WS_W1H + 16384)       // [256][256] f16  (n-major: W'[n][k] = W[k][n])
#define WS_W3H   (WS_W2H + 131072)
#define WS_W4H   (WS_W3H + 131072)
#define WS_W5H   (WS_W4H + 131072)     // [16][256] f16, cols 9..15 zero
#define WS_END   (WS_W5H + 8192)

// prep identical to R8-green (proven).
__global__ void prep_kernel(const float* __restrict__ emb, const int* __restrict__ traj,
                            const float* __restrict__ W1, const float* __restrict__ b1,
                            const float* __restrict__ W2, const float* __restrict__ W3,
                            const float* __restrict__ W4, const float* __restrict__ W5,
                            float* __restrict__ b1eff,
                            f16* __restrict__ W1h, f16* __restrict__ W2h,
                            f16* __restrict__ W3h, f16* __restrict__ W4h,
                            f16* __restrict__ W5h) {
  if (blockIdx.x == 816) {
    __shared__ float lat[128];
    int t = *traj;
    if (threadIdx.x < 128) lat[threadIdx.x] = emb[t * 128 + threadIdx.x];
    __syncthreads();
    int n = threadIdx.x;
    float s0 = 0.f, s1 = 0.f, s2 = 0.f, s3 = 0.f;
#pragma unroll 4
    for (int d = 0; d < 128; d += 4) {
      s0 = fmaf(lat[d + 0], W1[(25 + d) * 256 + n], s0);
      s1 = fmaf(lat[d + 1], W1[(26 + d) * 256 + n], s1);
      s2 = fmaf(lat[d + 2], W1[(27 + d) * 256 + n], s2);
      s3 = fmaf(lat[d + 3], W1[(28 + d) * 256 + n], s3);
    }
    b1eff[n] = b1[n] + ((s0 + s1) + (s2 + s3));
    return;
  }
  int i = blockIdx.x * 256 + threadIdx.x;
  if (i < 8192) {
    int n = i >> 5, k = i & 31;
    W1h[i] = (f16)((k < 25) ? W1[k * 256 + n] : 0.0f);
  } else if (i < 73728) {
    int j = i - 8192; int k = j >> 8, n = j & 255;
    W2h[n * 256 + k] = (f16)W2[j];
  } else if (i < 139264) {
    int j = i - 73728; int k = j >> 8, n = j & 255;
    W3h[n * 256 + k] = (f16)W3[j];
  } else if (i < 204800) {
    int j = i - 139264; int k = j >> 8, n = j & 255;
    W4h[n * 256 + k] = (f16)W4[j];
  } else if (i < 208896) {
    int j = i - 204800; int n = j >> 8, k = j & 255;
    W5h[j] = (f16)((n < 9) ? W5[k * 9 + n] : 0.0f);
  }
}

// R11-proven scalar exact-erf GELU (absmax 6.1e-5, zero scratch).
// DO NOT use packed f32x2 GELU (R13: +25MB scratch writes, slower).
// DO NOT move to f16 arithmetic (R6: 4.6e-4).
__device__ __forceinline__ float gelu_exact(float z) {
  float s = z * z;
  float q = fmaf(s, -1.8889263e-5f, 2.30872094e-4f);
  q = fmaf(s, q, -0.0023746714834f);
  q = fmaf(s, q, 0.01994711402007f);
  q = fmaf(s, q, -0.13298076013381f);
  q = fmaf(s, q, 0.79788456080287f);
  float t = z * q;          // erf(z/sqrt2)
  float u = 0.5f * z;
  return fmaf(u, t, u);     // 0.5 z (1 + erf)
}

// R18 = R11 compute body (scalar GELU, 197us fused, bit-proven) shrunk to
// 64-row blocks for occupancy: LDS 40192B -> 4 blocks/CU, 32 waves/CU (vs
// R13's 2/16). Barrier stalls in one block are covered by the other 3.
//
// RACE LESSON (R17 post-mortem): never give one thread two MFMA chains whose
// A-operand LDS ADDRESSES ARE IDENTICAL — the compiler CSEs the loads into
// one register feeding two acc chains = the R6/R7/R9 nondeterministic-fail
// pattern. Here every per-thread A-address is distinct (strips = different
// rows); only the slot-2 weight operand is shared (proven safe).
// Per-output accumulation order identical to R11 -> absmax 6.103516e-05.
__global__ __launch_bounds__(THREADS, 4) void fused_kernel(
    const float* __restrict__ Fg, const float* __restrict__ Cg,
    const f16* __restrict__ W1h, const f16* __restrict__ W2h,
    const f16* __restrict__ W3h, const f16* __restrict__ W4h,
    const f16* __restrict__ W5h,
    const float* __restrict__ b1eff, const float* __restrict__ b2,
    const float* __restrict__ b3, const float* __restrict__ b4,
    const float* __restrict__ b5, float* __restrict__ outg, int Btot) {
  __shared__ __align__(16) f16 hA[MROWS * HSTR];   // 33792B; float stage at end
  __shared__ __align__(16) char uFO[MROWS * 64];   // sFeat f16[64][32] early; o32 f32[64][16] late
  __shared__ __align__(16) float sR[MROWS * 9];    // polar rotation stash

  const int tid = threadIdx.x;
  const int lane = tid & 63;
  const int wv = tid >> 6;          // 0..7
  const int quad = lane >> 4;       // 16x16 shapes
  const int l15 = lane & 15;
  const int l31 = lane & 31;        // 32x32 shapes
  const int kh = lane >> 5;         // 0/1
  const int row0 = blockIdx.x * MROWS;

  // ---- Phase A: per-row strain features + polar rotation (threads 0..63, one row each)
  if (tid < MROWS) {
    const int grow = row0 + tid;
    float feat[25];
    float Rm[9];
    if (grow < Btot) {
      float Fm[9], Cm[9];
      const float* fp = Fg + grow * 9;
      const float* cp = Cg + grow * 9;
#pragma unroll
      for (int i = 0; i < 9; ++i) Fm[i] = fp[i];
#pragma unroll
      for (int i = 0; i < 9; ++i) Cm[i] = cp[i];
      float G[9];  // F^T F
#pragma unroll
      for (int i = 0; i < 3; ++i)
#pragma unroll
        for (int j = 0; j < 3; ++j)
          G[i * 3 + j] = Fm[i] * Fm[j] + Fm[3 + i] * Fm[3 + j] + Fm[6 + i] * Fm[6 + j];
      float det = Fm[0] * (Fm[4] * Fm[8] - Fm[5] * Fm[7])
                - Fm[1] * (Fm[3] * Fm[8] - Fm[5] * Fm[6])
                + Fm[2] * (Fm[3] * Fm[7] - Fm[4] * Fm[6]);
      // polar Newton: R <- 0.5 (R + R^-T); converges to the SVD rotation U Vh (det F > 0)
#pragma unroll
      for (int i = 0; i < 9; ++i) Rm[i] = Fm[i];
#pragma unroll
      for (int it = 0; it < 5; ++it) {
        float c0 = Rm[4]*Rm[8] - Rm[5]*Rm[7];
        float c1 = Rm[5]*Rm[6] - Rm[3]*Rm[8];
        float c2 = Rm[3]*Rm[7] - Rm[4]*Rm[6];
        float c3 = Rm[2]*Rm[7] - Rm[1]*Rm[8];
        float c4 = Rm[0]*Rm[8] - Rm[2]*Rm[6];
        float c5 = Rm[1]*Rm[6] - Rm[0]*Rm[7];
        float c6 = Rm[1]*Rm[5] - Rm[2]*Rm[4];
        float c7 = Rm[2]*Rm[3] - Rm[0]*Rm[5];
        float c8 = Rm[0]*Rm[4] - Rm[1]*Rm[3];
        float dr = Rm[0]*c0 + Rm[1]*c1 + Rm[2]*c2;
        float hv = 0.5f / dr;
        Rm[0] = 0.5f*Rm[0] + hv*c0; Rm[1] = 0.5f*Rm[1] + hv*c1; Rm[2] = 0.5f*Rm[2] + hv*c2;
        Rm[3] = 0.5f*Rm[3] + hv*c3; Rm[4] = 0.5f*Rm[4] + hv*c4; Rm[5] = 0.5f*Rm[5] + hv*c5;
        Rm[6] = 0.5f*Rm[6] + hv*c6; Rm[7] = 0.5f*Rm[7] + hv*c7; Rm[8] = 0.5f*Rm[8] + hv*c8;
      }
      // S = sym(R^T F); eigenvalues = singular values
      float s00 = Rm[0]*Fm[0] + Rm[3]*Fm[3] + Rm[6]*Fm[6];
      float s11 = Rm[1]*Fm[1] + Rm[4]*Fm[4] + Rm[7]*Fm[7];
      float s22 = Rm[2]*Fm[2] + Rm[5]*Fm[5] + Rm[8]*Fm[8];
      float s01 = 0.5f*((Rm[0]*Fm[1]+Rm[3]*Fm[4]+Rm[6]*Fm[7]) + (Rm[1]*Fm[0]+Rm[4]*Fm[3]+Rm[7]*Fm[6]));
      float s02 = 0.5f*((Rm[0]*Fm[2]+Rm[3]*Fm[5]+Rm[6]*Fm[8]) + (Rm[2]*Fm[0]+Rm[5]*Fm[3]+Rm[8]*Fm[6]));
      float s12 = 0.5f*((Rm[1]*Fm[2]+Rm[4]*Fm[5]+Rm[7]*Fm[8]) + (Rm[2]*Fm[1]+Rm[5]*Fm[4]+Rm[8]*Fm[7]));
      float q  = (s00 + s11 + s22) * (1.0f/3.0f);
      float p1 = s01*s01 + s02*s02 + s12*s12;
      float d0 = s00 - q, d1 = s11 - q, d2 = s22 - q;
      float p2 = d0*d0 + d1*d1 + d2*d2 + 2.0f*p1;
      float p  = sqrtf(p2 * (1.0f/6.0f));
      float e1, e2, e3;
      if (p > 1e-10f) {
        float pi = 1.0f / p;
        float b00 = d0*pi, b11 = d1*pi, b22 = d2*pi;
        float b01 = s01*pi, b02 = s02*pi, b12 = s12*pi;
        float detB = b00*(b11*b22 - b12*b12) - b01*(b01*b22 - b12*b02) + b02*(b01*b12 - b11*b02);
        float r = fminf(fmaxf(0.5f*detB, -1.0f), 1.0f);
        float phi = acosf(r) * (1.0f/3.0f);
        e1 = q + 2.0f * p * cosf(phi);
        e3 = q + 2.0f * p * cosf(phi + 2.0943951023931953f);
        e2 = 3.0f*q - e1 - e3;
      } else { e1 = q; e2 = q; e3 = q; }
      float f00 = fmaxf(Fm[0], 1e-6f);
      feat[0] = e1 - 1.0f; feat[1] = e2 - 1.0f; feat[2] = e3 - 1.0f;
#pragma unroll
      for (int k = 0; k < 9; ++k) feat[3 + k] = G[k];
      feat[3] -= 1.0f; feat[7] -= 1.0f; feat[11] -= 1.0f;
      feat[12] = det - 1.0f;
      feat[13] = logf(det) - 1.0f;
      feat[14] = f00 - 1.0f;
      feat[15] = logf(f00) - 1.0f;
#pragma unroll
      for (int k = 0; k < 9; ++k) feat[16 + k] = Cm[k];
    } else {
#pragma unroll
      for (int k = 0; k < 25; ++k) feat[k] = 0.0f;
#pragma unroll
      for (int k = 0; k < 9; ++k) Rm[k] = 0.0f;
    }
#pragma unroll
    for (int k = 0; k < 9; ++k) sR[tid * 9 + k] = Rm[k];
    // store f16 feats, A-frag friendly plain layout [row][32] into uFO
#pragma unroll
    for (int c = 0; c < 4; ++c) {
      f16x8 v;
#pragma unroll
      for (int j = 0; j < 8; ++j) {
        int k = c * 8 + j;
        v[j] = (f16)((k < 25) ? feat[k] : 0.0f);
      }
      *(f16x8*)(uFO + tid * 64 + c * 16) = v;
    }
  }
  __syncthreads();

  // ---- Layer 1 (16x16x32 MFMA, K=32): uFO(feats) -> hA. Wave wv owns cols [wv*32,+32).
  {
#pragma unroll
    for (int t = 0; t < 2; ++t) {
      const int col = wv * 32 + t * 16 + l15;
      f16x8 bfr = *(const f16x8*)(W1h + col * 32 + quad * 8);
      float bias = b1eff[col];
#pragma unroll
      for (int st = 0; st < 4; ++st) {             // 4 row-subtiles of 16 (64 rows)
        const int arow = st * 16 + l15;
        f16x8 a = *(const f16x8*)(uFO + arow * 64 + quad * 16);
        f32x4 acc = (f32x4){bias, bias, bias, bias};
        acc = __builtin_amdgcn_mfma_f32_16x16x32_f16(a, bfr, acc, 0, 0, 0);
#pragma unroll
        for (int r = 0; r < 4; ++r) {
          const int orow = st * 16 + quad * 4 + r;
          hA[orow * HSTR + col] = (f16)gelu_exact(acc[r]);
        }
      }
    }
  }
  __syncthreads();

  // ---- Hidden layers 2..4 (32x32x16 MFMA), IN-PLACE in hA. Wave wv owns cols
  // [wv*32,+32), TWO row-strips (rows l31, 32+l31: distinct A-addresses per
  // thread — no CSE hazard). Shared slot-2 weights only (R11-proven).
  // [reads+MFMA+gelu->regs] bar1 [writes only] bar2.
  const f16* Whs[3] = {W2h, W3h, W4h};
  const float* bgs[3] = {b2, b3, b4};
  const int col32 = wv * 32 + l31;
#pragma unroll 1
  for (int L = 0; L < 3; ++L) {
    const f16* Wh = Whs[L];
    const float bias = bgs[L][col32];
    f32x16 acc0, acc1;
#pragma unroll
    for (int r = 0; r < 16; ++r) { acc0[r] = bias; acc1[r] = bias; }
#pragma unroll
    for (int q = 0; q < 4; ++q) {                 // B in quarters: 16 VGPRs live
      f16x8 bq[4];
#pragma unroll
      for (int j = 0; j < 4; ++j)
        bq[j] = *(const f16x8*)(Wh + col32 * 256 + (q * 4 + j) * 16 + kh * 8);
#pragma unroll
      for (int j = 0; j < 4; ++j) {
        f16x8 a = *(const f16x8*)(hA + l31 * HSTR + (q * 4 + j) * 16 + kh * 8);
        acc0 = __builtin_amdgcn_mfma_f32_32x32x16_f16(a, bq[j], acc0, 0, 0, 0);
      }
#pragma unroll
      for (int j = 0; j < 4; ++j) {
        f16x8 a = *(const f16x8*)(hA + (32 + l31) * HSTR + (q * 4 + j) * 16 + kh * 8);
        acc1 = __builtin_amdgcn_mfma_f32_32x32x16_f16(a, bq[j], acc1, 0, 0, 0);
      }
    }
    // GELU + f16 convert into PRIVATE regs before the barrier (R10-proven hoist)
    f16 hv0[16], hv1[16];
#pragma unroll
    for (int r = 0; r < 16; ++r) {
      hv0[r] = (f16)gelu_exact(acc0[r]);
      hv1[r] = (f16)gelu_exact(acc1[r]);
    }
    __syncthreads();                              // all reads of hA done
#pragma unroll
    for (int r = 0; r < 16; ++r) {
      const int orow = (r & 3) + 8 * (r >> 2) + 4 * kh;
      hA[orow * HSTR + col32]        = hv0[r];
      hA[(32 + orow) * HSTR + col32] = hv1[r];
    }
    __syncthreads();                              // strip writes visible to all
  }

  // ---- Layer 5 (16x16x32, N=16, 9 valid): waves 0..3, wave wv rows [wv*16,+16)
  {
    float* o32 = (float*)uFO;                     // overlay: feats dead after L1
    if (wv < 4) {
      f16x8 bf5[8];
#pragma unroll
      for (int s = 0; s < 8; ++s)
        bf5[s] = *(const f16x8*)(W5h + l15 * 256 + s * 32 + quad * 8);
      const int arow = wv * 16 + l15;
      float bv = (l15 < 9) ? b5[l15] : 0.0f;
      f32x4 acc = (f32x4){bv, bv, bv, bv};
#pragma unroll
      for (int s = 0; s < 8; ++s) {
        f16x8 a = *(const f16x8*)(hA + arow * HSTR + s * 32 + quad * 8);
        acc = __builtin_amdgcn_mfma_f32_16x16x32_f16(a, bf5[s], acc, 0, 0, 0);
      }
#pragma unroll
      for (int r = 0; r < 4; ++r) {
        const int orow = wv * 16 + quad * 4 + r;
        o32[orow * 16 + l15] = acc[r];
      }
    }
  }
  __syncthreads();

  // ---- Final per-row: cauchy = R * sym(x) * F^T ; stage into hA region (free after L5)
  float* stage = (float*)hA;
  const float* o32c = (const float*)uFO;
  if (tid < MROWS && row0 + tid < Btot) {
    const float* x = o32c + tid * 16;
    const float* fp = Fg + (row0 + tid) * 9;   // F re-read (L2-hot); R from LDS stash
    float Fm[9], Rm[9];
#pragma unroll
    for (int i = 0; i < 9; ++i) Fm[i] = fp[i];
#pragma unroll
    for (int i = 0; i < 9; ++i) Rm[i] = sR[tid * 9 + i];
    float y[9];
    y[0] = x[0]; y[4] = x[4]; y[8] = x[8];
    y[1] = 0.5f * (x[1] + x[3]); y[3] = y[1];
    y[2] = 0.5f * (x[2] + x[6]); y[6] = y[2];
    y[5] = 0.5f * (x[5] + x[7]); y[7] = y[5];
    float P[9];
#pragma unroll
    for (int i = 0; i < 3; ++i)
#pragma unroll
      for (int j = 0; j < 3; ++j)
        P[i*3+j] = Rm[i*3]*y[j] + Rm[i*3+1]*y[3+j] + Rm[i*3+2]*y[6+j];
#pragma unroll
    for (int i = 0; i < 3; ++i)
#pragma unroll
      for (int j = 0; j < 3; ++j)
        stage[tid*9 + i*3 + j] = P[i*3]*Fm[j*3] + P[i*3+1]*Fm[j*3+1] + P[i*3+2]*Fm[j*3+2];
  }
  __syncthreads();
  for (int i = tid; i < MROWS * 9; i += THREADS) {
    int gi = row0 * 9 + i;
    if (gi < Btot * 9) outg[gi] = stage[i];
  }
}

extern "C" void kernel_launch(void* const* d_in, const int* in_sizes, int n_in,
                              void* d_out, int out_size, void* d_ws, size_t ws_size,
                              hipStream_t stream) {
  const float* Fg  = (const float*)d_in[0];
  const float* Cg  = (const float*)d_in[1];
  const float* emb = (const float*)d_in[2];
  const int*   trj = (const int*)d_in[3];
  const float* W1  = (const float*)d_in[4];
  const float* b1  = (const float*)d_in[5];
  const float* W2  = (const float*)d_in[6];
  const float* b2  = (const float*)d_in[7];
  const float* W3  = (const float*)d_in[8];
  const float* b3  = (const float*)d_in[9];
  const float* W4  = (const float*)d_in[10];
  const float* b4  = (const float*)d_in[11];
  const float* W5  = (const float*)d_in[12];
  const float* b5  = (const float*)d_in[13];
  float* outg = (float*)d_out;
  const int Btot = in_sizes[0] / 9;

  char* ws = (char*)d_ws;
  float* b1eff = (float*)(ws + WS_B1EFF);
  f16* W1h = (f16*)(ws + WS_W1H);
  f16* W2h = (f16*)(ws + WS_W2H);
  f16* W3h = (f16*)(ws + WS_W3H);
  f16* W4h = (f16*)(ws + WS_W4H);
  f16* W5h = (f16*)(ws + WS_W5H);

  prep_kernel<<<817, 256, 0, stream>>>(emb, trj, W1, b1, W2, W3, W4, W5,
                                       b1eff, W1h, W2h, W3h, W4h, W5h);
  const int grid = (Btot + MROWS - 1) / MROWS;
  fused_kernel<<<grid, THREADS, 0, stream>>>(Fg, Cg, W1h, W2h, W3h, W4h, W5h,
                                             b1eff, b2, b3, b4, b5, outg, Btot);
}

// Round 8
// 264.232 us; speedup vs baseline: 1.7781x; 1.2205x over previous
//
#include <hip/hip_runtime.h>

typedef _Float16 f16;
typedef _Float16 f16x8 __attribute__((ext_vector_type(8)));
typedef float f32x4 __attribute__((ext_vector_type(4)));
typedef float f32x16 __attribute__((ext_vector_type(16)));

#define MROWS 128
#define THREADS 512
#define HSTR 264   // f16/row: 528B, 16B-aligned rows (HSTR must be mult. of 8)

// d_ws layout (bytes) — identical to R8/R11 (proven)
#define WS_B1EFF 0                      // 256 f32
#define WS_W1H   1024                   // [256][32] f16 (n-major, k<25 valid, rest 0)
#define WS_W2H   (WS_W1H + 16384)       // [256][256] f16  (n-major: W'[n][k] = W[k][n])
#define WS_W3H   (WS_W2H + 131072)
#define WS_W4H   (WS_W3H + 131072)
#define WS_W5H   (WS_W4H + 131072)     // [16][256] f16, cols 9..15 zero
#define WS_END   (WS_W5H + 8192)

// R19 prep: same OUTPUT BYTES as R8-green prep (d_ws bit-identical), but the
// W2/3/4 transpose is LDS-tiled for coalescing. Old prep: 1 elem/thread,
// scattered 2B writes at 512B stride (64 cache lines per wave) — the only
// kernel that can explain the ~60us e2e-minus-fused gap. New: 64x64 tiles,
// 256B-coalesced reads, LDS stride-66 f16 (bank = lane mod 32: conflict-free),
// 128B-coalesced writes. Grid 817 -> 51 blocks.
__global__ void prep_kernel(const float* __restrict__ emb, const int* __restrict__ traj,
                            const float* __restrict__ W1, const float* __restrict__ b1,
                            const float* __restrict__ W2, const float* __restrict__ W3,
                            const float* __restrict__ W4, const float* __restrict__ W5,
                            float* __restrict__ b1eff,
                            f16* __restrict__ W1h, f16* __restrict__ W2h,
                            f16* __restrict__ W3h, f16* __restrict__ W4h,
                            f16* __restrict__ W5h) {
  __shared__ __align__(16) f16 ld[64 * 66];
  const int b = blockIdx.x;
  const int tid = threadIdx.x;
  if (b < 48) {                      // W2/3/4 transpose, 16 tiles of 64x64 each
    const float* src = (b < 16) ? W2 : (b < 32) ? W3 : W4;
    f16* dst = (b < 16) ? W2h : (b < 32) ? W3h : W4h;
    const int t = b & 15;
    const int k0 = (t >> 2) * 64, n0 = (t & 3) * 64;
#pragma unroll
    for (int rep = 0; rep < 16; ++rep) {     // read rows of src (coalesced 256B)
      int idx = rep * 256 + tid;
      int kk = idx >> 6, nn = idx & 63;
      ld[kk * 66 + nn] = (f16)src[(k0 + kk) * 256 + n0 + nn];
    }
    __syncthreads();
#pragma unroll
    for (int rep = 0; rep < 16; ++rep) {     // write rows of dst (coalesced 128B)
      int idx = rep * 256 + tid;
      int nn = idx >> 6, kk = idx & 63;      // lds read: stride 66 f16 -> bank=lane%32, free
      dst[(n0 + nn) * 256 + k0 + kk] = ld[kk * 66 + nn];
    }
    return;
  }
  if (b == 48) {                     // W1h: [256 n][32 k], k<25 valid (same mapping as R8)
#pragma unroll 1
    for (int e = 0; e < 32; ++e) {
      int i = e * 256 + tid;
      int n = i >> 5, k = i & 31;
      W1h[i] = (f16)((k < 25) ? W1[k * 256 + n] : 0.0f);
    }
    return;
  }
  if (b == 49) {                     // W5h: [16 n][256 k], n<9 valid (same mapping as R8)
#pragma unroll 1
    for (int e = 0; e < 32; ++e) {
      int j = e * 256 + tid;
      int n = j >> 8, k = j & 255;
      W5h[j] = (f16)((n < 9) ? W5[k * 9 + n] : 0.0f);
    }
    return;
  }
  // b == 50: b1eff = b1 + W1[25:153]^T . emb[traj]  (identical to R8-green)
  {
    __shared__ float lat[128];
    int t = *traj;
    if (tid < 128) lat[tid] = emb[t * 128 + tid];
    __syncthreads();
    int n = tid;
    if (n < 256) {
      float s0 = 0.f, s1 = 0.f, s2 = 0.f, s3 = 0.f;
#pragma unroll 4
      for (int d = 0; d < 128; d += 4) {
        s0 = fmaf(lat[d + 0], W1[(25 + d) * 256 + n], s0);
        s1 = fmaf(lat[d + 1], W1[(26 + d) * 256 + n], s1);
        s2 = fmaf(lat[d + 2], W1[(27 + d) * 256 + n], s2);
        s3 = fmaf(lat[d + 3], W1[(28 + d) * 256 + n], s3);
      }
      b1eff[n] = b1[n] + ((s0 + s1) + (s2 + s3));
    }
  }
}

// exact-erf GELU in f32 (z^2-form): proven absmax 6.1e-5 path. DO NOT move to f16
// arithmetic (R6: 4.6e-4) and DO NOT give one thread two MFMA chains whose
// A-operand LDS addresses are identical — compiler CSEs the loads into one
// register feeding two acc chains = R6/R7/R9/R17 nondeterministic fail.
// Sequential per-tile loops with DISTINCT A-addresses sharing B regs are proven.
__device__ __forceinline__ float gelu_exact(float z) {
  float s = z * z;
  float q = fmaf(s, -1.8889263e-5f, 2.30872094e-4f);
  q = fmaf(s, q, -0.0023746714834f);
  q = fmaf(s, q, 0.01994711402007f);
  q = fmaf(s, q, -0.13298076013381f);
  q = fmaf(s, q, 0.79788456080287f);
  float t = z * q;          // erf(z/sqrt2)
  float u = 0.5f * z;
  return fmaf(u, t, u);     // 0.5 z (1 + erf)
}

// R19 fused = EXACT Round-0 baseline (best proven: 196.8us fused / 264.9 e2e).
// R12-R18 established: (1) VALU issue is not the critical path (R13: VALU
// 46->29% at equal time); (2) register-resident activations spill (128-arch
// VGPR cap at 8-wave blocks; R14-16); (3) smaller blocks lose on weight-load
// amortization (R18: 64 rows -> MfmaUtil 24->18). 128 rows x 2 blk/CU at
// 64 VGPR + 64 AGPR is the structural sweet spot. Per-element summation order
// is the R8/R11-proven one -> absmax 6.103516e-05.
// LDS: hA 67.6KB + (sFeat|o32 overlay) 8KB + sR 4.6KB ~= 80.4KB -> 2 blocks/CU.
__global__ __launch_bounds__(THREADS, 4) void fused_kernel(
    const float* __restrict__ Fg, const float* __restrict__ Cg,
    const f16* __restrict__ W1h, const f16* __restrict__ W2h,
    const f16* __restrict__ W3h, const f16* __restrict__ W4h,
    const f16* __restrict__ W5h,
    const float* __restrict__ b1eff, const float* __restrict__ b2,
    const float* __restrict__ b3, const float* __restrict__ b4,
    const float* __restrict__ b5, float* __restrict__ outg, int Btot) {
  __shared__ __align__(16) f16 hA[MROWS * HSTR];   // activations; reused as float stage at end
  __shared__ __align__(16) char uFO[MROWS * 64];   // sFeat f16[128][32] early; o32 f32[128][16] late
  __shared__ __align__(16) float sR[MROWS * 9];    // polar rotation stash (phase A -> final)

  const int tid = threadIdx.x;
  const int lane = tid & 63;
  const int wv = tid >> 6;          // 0..7
  const int quad = lane >> 4;       // 16x16 shapes
  const int l15 = lane & 15;
  const int l31 = lane & 31;        // 32x32 shapes
  const int kh = lane >> 5;         // 0/1
  const int row0 = blockIdx.x * MROWS;

  // ---- Phase A: per-row strain features + polar rotation (threads 0..127, one row each)
  if (tid < MROWS) {
    const int grow = row0 + tid;
    float feat[25];
    float Rm[9];
    if (grow < Btot) {
      float Fm[9], Cm[9];
      const float* fp = Fg + grow * 9;
      const float* cp = Cg + grow * 9;
#pragma unroll
      for (int i = 0; i < 9; ++i) Fm[i] = fp[i];
#pragma unroll
      for (int i = 0; i < 9; ++i) Cm[i] = cp[i];
      float G[9];  // F^T F
#pragma unroll
      for (int i = 0; i < 3; ++i)
#pragma unroll
        for (int j = 0; j < 3; ++j)
          G[i * 3 + j] = Fm[i] * Fm[j] + Fm[3 + i] * Fm[3 + j] + Fm[6 + i] * Fm[6 + j];
      float det = Fm[0] * (Fm[4] * Fm[8] - Fm[5] * Fm[7])
                - Fm[1] * (Fm[3] * Fm[8] - Fm[5] * Fm[6])
                + Fm[2] * (Fm[3] * Fm[7] - Fm[4] * Fm[6]);
      // polar Newton: R <- 0.5 (R + R^-T); converges to the SVD rotation U Vh (det F > 0)
#pragma unroll
      for (int i = 0; i < 9; ++i) Rm[i] = Fm[i];
#pragma unroll
      for (int it = 0; it < 5; ++it) {
        float c0 = Rm[4]*Rm[8] - Rm[5]*Rm[7];
        float c1 = Rm[5]*Rm[6] - Rm[3]*Rm[8];
        float c2 = Rm[3]*Rm[7] - Rm[4]*Rm[6];
        float c3 = Rm[2]*Rm[7] - Rm[1]*Rm[8];
        float c4 = Rm[0]*Rm[8] - Rm[2]*Rm[6];
        float c5 = Rm[1]*Rm[6] - Rm[0]*Rm[7];
        float c6 = Rm[1]*Rm[5] - Rm[2]*Rm[4];
        float c7 = Rm[2]*Rm[3] - Rm[0]*Rm[5];
        float c8 = Rm[0]*Rm[4] - Rm[1]*Rm[3];
        float dr = Rm[0]*c0 + Rm[1]*c1 + Rm[2]*c2;
        float hv = 0.5f / dr;
        Rm[0] = 0.5f*Rm[0] + hv*c0; Rm[1] = 0.5f*Rm[1] + hv*c1; Rm[2] = 0.5f*Rm[2] + hv*c2;
        Rm[3] = 0.5f*Rm[3] + hv*c3; Rm[4] = 0.5f*Rm[4] + hv*c4; Rm[5] = 0.5f*Rm[5] + hv*c5;
        Rm[6] = 0.5f*Rm[6] + hv*c6; Rm[7] = 0.5f*Rm[7] + hv*c7; Rm[8] = 0.5f*Rm[8] + hv*c8;
      }
      // S = sym(R^T F); eigenvalues = singular values (descending via trig formula)
      float s00 = Rm[0]*Fm[0] + Rm[3]*Fm[3] + Rm[6]*Fm[6];
      float s11 = Rm[1]*Fm[1] + Rm[4]*Fm[4] + Rm[7]*Fm[7];
      float s22 = Rm[2]*Fm[2] + Rm[5]*Fm[5] + Rm[8]*Fm[8];
      float s01 = 0.5f*((Rm[0]*Fm[1]+Rm[3]*Fm[4]+Rm[6]*Fm[7]) + (Rm[1]*Fm[0]+Rm[4]*Fm[3]+Rm[7]*Fm[6]));
      float s02 = 0.5f*((Rm[0]*Fm[2]+Rm[3]*Fm[5]+Rm[6]*Fm[8]) + (Rm[2]*Fm[0]+Rm[5]*Fm[3]+Rm[8]*Fm[6]));
      float s12 = 0.5f*((Rm[1]*Fm[2]+Rm[4]*Fm[5]+Rm[7]*Fm[8]) + (Rm[2]*Fm[1]+Rm[5]*Fm[4]+Rm[8]*Fm[7]));
      float q  = (s00 + s11 + s22) * (1.0f/3.0f);
      float p1 = s01*s01 + s02*s02 + s12*s12;
      float d0 = s00 - q, d1 = s11 - q, d2 = s22 - q;
      float p2 = d0*d0 + d1*d1 + d2*d2 + 2.0f*p1;
      float p  = sqrtf(p2 * (1.0f/6.0f));
      float e1, e2, e3;
      if (p > 1e-10f) {
        float pi = 1.0f / p;
        float b00 = d0*pi, b11 = d1*pi, b22 = d2*pi;
        float b01 = s01*pi, b02 = s02*pi, b12 = s12*pi;
        float detB = b00*(b11*b22 - b12*b12) - b01*(b01*b22 - b12*b02) + b02*(b01*b12 - b11*b02);
        float r = fminf(fmaxf(0.5f*detB, -1.0f), 1.0f);
        float phi = acosf(r) * (1.0f/3.0f);
        e1 = q + 2.0f * p * cosf(phi);
        e3 = q + 2.0f * p * cosf(phi + 2.0943951023931953f);
        e2 = 3.0f*q - e1 - e3;
      } else { e1 = q; e2 = q; e3 = q; }
      float f00 = fmaxf(Fm[0], 1e-6f);
      feat[0] = e1 - 1.0f; feat[1] = e2 - 1.0f; feat[2] = e3 - 1.0f;
#pragma unroll
      for (int k = 0; k < 9; ++k) feat[3 + k] = G[k];
      feat[3] -= 1.0f; feat[7] -= 1.0f; feat[11] -= 1.0f;
      feat[12] = det - 1.0f;
      feat[13] = logf(det) - 1.0f;
      feat[14] = f00 - 1.0f;
      feat[15] = logf(f00) - 1.0f;
#pragma unroll
      for (int k = 0; k < 9; ++k) feat[16 + k] = Cm[k];
    } else {
#pragma unroll
      for (int k = 0; k < 25; ++k) feat[k] = 0.0f;
#pragma unroll
      for (int k = 0; k < 9; ++k) Rm[k] = 0.0f;
    }
#pragma unroll
    for (int k = 0; k < 9; ++k) sR[tid * 9 + k] = Rm[k];
    // store f16 feats, A-frag friendly plain layout [row][32] into uFO
#pragma unroll
    for (int c = 0; c < 4; ++c) {
      f16x8 v;
#pragma unroll
      for (int j = 0; j < 8; ++j) {
        int k = c * 8 + j;
        v[j] = (f16)((k < 25) ? feat[k] : 0.0f);
      }
      *(f16x8*)(uFO + tid * 64 + c * 16) = v;
    }
  }
  __syncthreads();

  // ---- Layer 1 (16x16x32 MFMA, K=32): uFO(feats) -> hA. Wave wv owns cols [wv*32,+32).
  {
#pragma unroll
    for (int t = 0; t < 2; ++t) {
      const int col = wv * 32 + t * 16 + l15;
      f16x8 bfr = *(const f16x8*)(W1h + col * 32 + quad * 8);
      float bias = b1eff[col];
#pragma unroll
      for (int st = 0; st < 8; ++st) {             // 8 row-subtiles of 16
        const int arow = st * 16 + l15;
        f16x8 a = *(const f16x8*)(uFO + arow * 64 + quad * 16);
        f32x4 acc = (f32x4){bias, bias, bias, bias};
        acc = __builtin_amdgcn_mfma_f32_16x16x32_f16(a, bfr, acc, 0, 0, 0);
#pragma unroll
        for (int r = 0; r < 4; ++r) {
          const int orow = st * 16 + quad * 4 + r;
          hA[orow * HSTR + col] = (f16)gelu_exact(acc[r]);
        }
      }
    }
  }
  __syncthreads();

  // ---- Hidden layers 2..4 (32x32x16 MFMA), IN-PLACE in hA. Wave wv owns cols
  // [wv*32,+32), 4 sequential row-tiles (R8-proven loop shape, acc chains NOT interleaved).
  // [reads+MFMA+gelu->regs] bar1 [writes only] bar2.
  const f16* Whs[3] = {W2h, W3h, W4h};
  const float* bgs[3] = {b2, b3, b4};
  const int col32 = wv * 32 + l31;
#pragma unroll 1
  for (int L = 0; L < 3; ++L) {
    const f16* Wh = Whs[L];
    const float bias = bgs[L][col32];
    f32x16 acc0, acc1, acc2, acc3;
#pragma unroll
    for (int r = 0; r < 16; ++r) { acc0[r] = bias; acc1[r] = bias; acc2[r] = bias; acc3[r] = bias; }
#pragma unroll
    for (int q = 0; q < 4; ++q) {                 // B in quarters: 16 VGPRs live
      f16x8 bq[4];
#pragma unroll
      for (int j = 0; j < 4; ++j)
        bq[j] = *(const f16x8*)(Wh + col32 * 256 + (q * 4 + j) * 16 + kh * 8);
#pragma unroll
      for (int j = 0; j < 4; ++j) {
        f16x8 a = *(const f16x8*)(hA + l31 * HSTR + (q * 4 + j) * 16 + kh * 8);
        acc0 = __builtin_amdgcn_mfma_f32_32x32x16_f16(a, bq[j], acc0, 0, 0, 0);
      }
#pragma unroll
      for (int j = 0; j < 4; ++j) {
        f16x8 a = *(const f16x8*)(hA + (32 + l31) * HSTR + (q * 4 + j) * 16 + kh * 8);
        acc1 = __builtin_amdgcn_mfma_f32_32x32x16_f16(a, bq[j], acc1, 0, 0, 0);
      }
#pragma unroll
      for (int j = 0; j < 4; ++j) {
        f16x8 a = *(const f16x8*)(hA + (64 + l31) * HSTR + (q * 4 + j) * 16 + kh * 8);
        acc2 = __builtin_amdgcn_mfma_f32_32x32x16_f16(a, bq[j], acc2, 0, 0, 0);
      }
#pragma unroll
      for (int j = 0; j < 4; ++j) {
        f16x8 a = *(const f16x8*)(hA + (96 + l31) * HSTR + (q * 4 + j) * 16 + kh * 8);
        acc3 = __builtin_amdgcn_mfma_f32_32x32x16_f16(a, bq[j], acc3, 0, 0, 0);
      }
    }
    // GELU + f16 convert into PRIVATE regs before the barrier (R10-proven hoist)
    f16 hv0[16], hv1[16], hv2[16], hv3[16];
#pragma unroll
    for (int r = 0; r < 16; ++r) {
      hv0[r] = (f16)gelu_exact(acc0[r]);
      hv1[r] = (f16)gelu_exact(acc1[r]);
      hv2[r] = (f16)gelu_exact(acc2[r]);
      hv3[r] = (f16)gelu_exact(acc3[r]);
    }
    __syncthreads();                              // all reads of hA done
#pragma unroll
    for (int r = 0; r < 16; ++r) {
      const int orow = (r & 3) + 8 * (r >> 2) + 4 * kh;
      hA[orow * HSTR + col32]        = hv0[r];
      hA[(32 + orow) * HSTR + col32] = hv1[r];
      hA[(64 + orow) * HSTR + col32] = hv2[r];
      hA[(96 + orow) * HSTR + col32] = hv3[r];
    }
    __syncthreads();                              // strip writes visible to all
  }

  // ---- Layer 5 (16x16x32, N=16, 9 valid): all 8 waves, wave wv rows [wv*16,+16); reads hA
  {
    float* o32 = (float*)uFO;                     // overlay: feats dead after L1
    f16x8 bf5[8];
#pragma unroll
    for (int s = 0; s < 8; ++s)
      bf5[s] = *(const f16x8*)(W5h + l15 * 256 + s * 32 + quad * 8);
    const int arow = wv * 16 + l15;
    float bv = (l15 < 9) ? b5[l15] : 0.0f;
    f32x4 acc = (f32x4){bv, bv, bv, bv};
#pragma unroll
    for (int s = 0; s < 8; ++s) {
      f16x8 a = *(const f16x8*)(hA + arow * HSTR + s * 32 + quad * 8);
      acc = __builtin_amdgcn_mfma_f32_16x16x32_f16(a, bf5[s], acc, 0, 0, 0);
    }
#pragma unroll
    for (int r = 0; r < 4; ++r) {
      const int orow = wv * 16 + quad * 4 + r;
      o32[orow * 16 + l15] = acc[r];
    }
  }
  __syncthreads();

  // ---- Final per-row: cauchy = R * sym(x) * F^T ; stage into hA region (free after L5)
  float* stage = (float*)hA;
  const float* o32c = (const float*)uFO;
  if (tid < MROWS && row0 + tid < Btot) {
    const float* x = o32c + tid * 16;
    const float* fp = Fg + (row0 + tid) * 9;   // F re-read (L2-hot); R from LDS stash
    float Fm[9], Rm[9];
#pragma unroll
    for (int i = 0; i < 9; ++i) Fm[i] = fp[i];
#pragma unroll
    for (int i = 0; i < 9; ++i) Rm[i] = sR[tid * 9 + i];
    float y[9];
    y[0] = x[0]; y[4] = x[4]; y[8] = x[8];
    y[1] = 0.5f * (x[1] + x[3]); y[3] = y[1];
    y[2] = 0.5f * (x[2] + x[6]); y[6] = y[2];
    y[5] = 0.5f * (x[5] + x[7]); y[7] = y[5];
    float P[9];
#pragma unroll
    for (int i = 0; i < 3; ++i)
#pragma unroll
      for (int j = 0; j < 3; ++j)
        P[i*3+j] = Rm[i*3]*y[j] + Rm[i*3+1]*y[3+j] + Rm[i*3+2]*y[6+j];
#pragma unroll
    for (int i = 0; i < 3; ++i)
#pragma unroll
      for (int j = 0; j < 3; ++j)
        stage[tid*9 + i*3 + j] = P[i*3]*Fm[j*3] + P[i*3+1]*Fm[j*3+1] + P[i*3+2]*Fm[j*3+2];
  }
  __syncthreads();
  for (int i = tid; i < MROWS * 9; i += THREADS) {
    int gi = row0 * 9 + i;
    if (gi < Btot * 9) outg[gi] = stage[i];
  }
}

extern "C" void kernel_launch(void* const* d_in, const int* in_sizes, int n_in,
                              void* d_out, int out_size, void* d_ws, size_t ws_size,
                              hipStream_t stream) {
  const float* Fg  = (const float*)d_in[0];
  const float* Cg  = (const float*)d_in[1];
  const float* emb = (const float*)d_in[2];
  const int*   trj = (const int*)d_in[3];
  const float* W1  = (const float*)d_in[4];
  const float* b1  = (const float*)d_in[5];
  const float* W2  = (const float*)d_in[6];
  const float* b2  = (const float*)d_in[7];
  const float* W3  = (const float*)d_in[8];
  const float* b3  = (const float*)d_in[9];
  const float* W4  = (const float*)d_in[10];
  const float* b4  = (const float*)d_in[11];
  const float* W5  = (const float*)d_in[12];
  const float* b5  = (const float*)d_in[13];
  float* outg = (float*)d_out;
  const int Btot = in_sizes[0] / 9;

  char* ws = (char*)d_ws;
  float* b1eff = (float*)(ws + WS_B1EFF);
  f16* W1h = (f16*)(ws + WS_W1H);
  f16* W2h = (f16*)(ws + WS_W2H);
  f16* W3h = (f16*)(ws + WS_W3H);
  f16* W4h = (f16*)(ws + WS_W4H);
  f16* W5h = (f16*)(ws + WS_W5H);

  prep_kernel<<<51, 256, 0, stream>>>(emb, trj, W1, b1, W2, W3, W4, W5,
                                      b1eff, W1h, W2h, W3h, W4h, W5h);
  const int grid = (Btot + MROWS - 1) / MROWS;
  fused_kernel<<<grid, THREADS, 0, stream>>>(Fg, Cg, W1h, W2h, W3h, W4h, W5h,
                                             b1eff, b2, b3, b4, b5, outg, Btot);
}